// Round 1
// baseline (21257.184 us; speedup 1.0000x reference)
//
#include <hip/hip_runtime.h>
#include <math.h>

#define NB 16384   // batch
#define DD 64      // state dim
#define HH 256     // ODE hidden
#define NSTEP 63   // T-1
#define RR 32      // rows per block
#define NT 256     // threads per block
#define AS 68      // LDS stride for 64-wide buffers (y, actor h) : 68 % 32 words -> 4*r banks
#define HS 260     // LDS stride for 256-wide buffers (h1, h2)

__device__ __forceinline__ float fast_tanh(float x) {
    float a = fabsf(x);
    float e = __expf(-2.0f * a);
    float r = (1.0f - e) / (1.0f + e);
    return copysignf(r, x);
}
__device__ __forceinline__ float fast_softplus(float x) {
    return fmaxf(x, 0.0f) + __logf(1.0f + __expf(-fabsf(x)));
}
__device__ __forceinline__ float clean_f(float x) {
    return isfinite(x) ? x : 0.0f;
}

// narrow layer: [R x 64] = in_s[R x 64] @ W[64 x 64] + b ; this thread: rows w*8..w*8+7, col l
__device__ __forceinline__ void mm64(const float* in_s,
                                     const float* __restrict__ W,
                                     const float* __restrict__ b,
                                     int w, int l, float acc[8]) {
    const float bb = b[l];
#pragma unroll
    for (int i = 0; i < 8; ++i) acc[i] = bb;
#pragma unroll 4
    for (int k = 0; k < 64; k += 4) {
        const float w0 = W[(k + 0) * 64 + l];
        const float w1 = W[(k + 1) * 64 + l];
        const float w2 = W[(k + 2) * 64 + l];
        const float w3 = W[(k + 3) * 64 + l];
#pragma unroll
        for (int i = 0; i < 8; ++i) {
            const float4 v = *(const float4*)&in_s[(w * 8 + i) * AS + k];
            float a = acc[i];
            a = fmaf(v.x, w0, a);
            a = fmaf(v.y, w1, a);
            a = fmaf(v.z, w2, a);
            a = fmaf(v.w, w3, a);
            acc[i] = a;
        }
    }
}

// wide layer: [R x 256] = in_s[R x K] @ W[K x 256] + b, activation, -> out_s (stride HS)
// this thread: rows rg*8..rg*8+7 (bank-staggered), cols c0..c0+3
template <int K, int ACT>  // ACT: 0 = tanh, 1 = softplus
__device__ __forceinline__ void mmwide(const float* in_s, int istride,
                                       const float* __restrict__ W,
                                       const float* __restrict__ b,
                                       float* out_s, int rg, int c0) {
    float4 acc[8];
    const float4 bias = *(const float4*)&b[c0];
#pragma unroll
    for (int i = 0; i < 8; ++i) acc[i] = bias;
#pragma unroll 2
    for (int k = 0; k < K; k += 4) {
        const float4 wa = *(const float4*)&W[(k + 0) * HH + c0];
        const float4 wb = *(const float4*)&W[(k + 1) * HH + c0];
        const float4 wc = *(const float4*)&W[(k + 2) * HH + c0];
        const float4 wd = *(const float4*)&W[(k + 3) * HH + c0];
#pragma unroll
        for (int ii = 0; ii < 8; ++ii) {
            const int i = (ii + rg) & 7;  // stagger rows across lanes -> distinct LDS banks
            const float4 v = *(const float4*)&in_s[(rg * 8 + i) * istride + k];
            float4 a = acc[i];
            a.x = fmaf(v.x, wa.x, a.x); a.y = fmaf(v.x, wa.y, a.y);
            a.z = fmaf(v.x, wa.z, a.z); a.w = fmaf(v.x, wa.w, a.w);
            a.x = fmaf(v.y, wb.x, a.x); a.y = fmaf(v.y, wb.y, a.y);
            a.z = fmaf(v.y, wb.z, a.z); a.w = fmaf(v.y, wb.w, a.w);
            a.x = fmaf(v.z, wc.x, a.x); a.y = fmaf(v.z, wc.y, a.y);
            a.z = fmaf(v.z, wc.z, a.z); a.w = fmaf(v.z, wc.w, a.w);
            a.x = fmaf(v.w, wd.x, a.x); a.y = fmaf(v.w, wd.y, a.y);
            a.z = fmaf(v.w, wd.z, a.z); a.w = fmaf(v.w, wd.w, a.w);
            acc[i] = a;
        }
    }
#pragma unroll
    for (int i = 0; i < 8; ++i) {
        float4 o = acc[i];
        if (ACT == 0) {
            o.x = fast_tanh(o.x); o.y = fast_tanh(o.y);
            o.z = fast_tanh(o.z); o.w = fast_tanh(o.w);
        } else {
            o.x = fast_softplus(o.x); o.y = fast_softplus(o.y);
            o.z = fast_softplus(o.z); o.w = fast_softplus(o.w);
        }
        *(float4*)&out_s[(rg * 8 + i) * HS + c0] = o;
    }
}

extern "C" __global__ void __launch_bounds__(NT, 2)
ode_sac_kernel(const float* __restrict__ y0,
               const float* __restrict__ tarr,
               const float* __restrict__ noise,
               const float* __restrict__ oW1, const float* __restrict__ ob1,
               const float* __restrict__ oW2, const float* __restrict__ ob2,
               const float* __restrict__ oW3, const float* __restrict__ ob3,
               const float* __restrict__ amW1, const float* __restrict__ amb1,
               const float* __restrict__ amW2, const float* __restrict__ amb2,
               const float* __restrict__ amW3, const float* __restrict__ amb3,
               const float* __restrict__ asW1, const float* __restrict__ asb1,
               const float* __restrict__ asW2, const float* __restrict__ asb2,
               const float* __restrict__ asW3, const float* __restrict__ asb3,
               float* __restrict__ out) {
    __shared__ __align__(16) float lds[RR * AS + 2 * RR * HS];  // 75264 B
    float* y_s  = lds;                 // [32][68]
    float* h1_s = lds + RR * AS;       // [32][260], reused as actor ping buffer
    float* h2_s = h1_s + RR * HS;      // [32][260], reused as actor pong buffer
    float* a1_s = h1_s;
    float* a2_s = h2_s;

    const int tid  = threadIdx.x;
    const int w    = tid >> 6;   // wave 0..3
    const int l    = tid & 63;   // lane
    const int row0 = blockIdx.x * RR;

    const int rg = l >> 4;                       // wide-layer row group 0..3
    const int c0 = (w * 16 + (l & 15)) * 4;      // wide-layer column base 0..252

    const float dt = tarr[1] - tarr[0];

    // load y0 into LDS, emit out[0] = y0
#pragma unroll
    for (int i = 0; i < 8; ++i) {
        const int r = w * 8 + i;
        const float v = y0[(size_t)(row0 + r) * DD + l];
        y_s[r * AS + l] = v;
        out[(size_t)(row0 + r) * DD + l] = v;
    }
    __syncthreads();

    for (int t = 0; t < NSTEP; ++t) {
        float meanr[8];
        float ur[8];

        // ---- actor mean head ----
        {   // A1: a1 = relu(y @ amW1 + amb1)
            float acc[8];
            mm64(y_s, amW1, amb1, w, l, acc);
#pragma unroll
            for (int i = 0; i < 8; ++i) a1_s[(w * 8 + i) * AS + l] = fmaxf(acc[i], 0.0f);
        }
        __syncthreads();
        {   // A2: a2 = relu(a1 @ amW2 + amb2)
            float acc[8];
            mm64(a1_s, amW2, amb2, w, l, acc);
#pragma unroll
            for (int i = 0; i < 8; ++i) a2_s[(w * 8 + i) * AS + l] = fmaxf(acc[i], 0.0f);
        }
        __syncthreads();
        {   // A3: mean = clean(tanh(a2 @ amW3 + amb3))  (registers only)
            float acc[8];
            mm64(a2_s, amW3, amb3, w, l, acc);
#pragma unroll
            for (int i = 0; i < 8; ++i) meanr[i] = clean_f(fast_tanh(acc[i]));
        }
        // ---- actor log_std head ----  (a1 region free: last read was A2, behind a barrier)
        {   // S1: a1 = relu(y @ asW1 + asb1)
            float acc[8];
            mm64(y_s, asW1, asb1, w, l, acc);
#pragma unroll
            for (int i = 0; i < 8; ++i) a1_s[(w * 8 + i) * AS + l] = fmaxf(acc[i], 0.0f);
        }
        __syncthreads();
        {   // S2: a2 = relu(a1 @ asW2 + asb2)
            float acc[8];
            mm64(a1_s, asW2, asb2, w, l, acc);
#pragma unroll
            for (int i = 0; i < 8; ++i) a2_s[(w * 8 + i) * AS + l] = fmaxf(acc[i], 0.0f);
        }
        __syncthreads();
        {   // S3: log_std -> std -> x_t -> u  (registers only)
            float acc[8];
            mm64(a2_s, asW3, asb3, w, l, acc);
#pragma unroll
            for (int i = 0; i < 8; ++i) {
                const float ls = clean_f(acc[i]);
                const float sd = fast_softplus(ls);
                const float ep = noise[(size_t)t * NB * DD + (size_t)(row0 + w * 8 + i) * DD + l];
                ur[i] = fast_tanh(meanr[i] + sd * ep);
            }
        }
        // ---- ODE func ----  (h1 region free: a1 last read at S2, behind a barrier)
        // B1: h1 = tanh(y @ oW1 + ob1)
        mmwide<DD, 0>(y_s, AS, oW1, ob1, h1_s, rg, c0);
        __syncthreads();   // h1 written; also guarantees all S3 reads of a2 are done
        // B2: h2 = softplus(h1 @ oW2 + ob2)
        mmwide<HH, 1>(h1_s, HS, oW2, ob2, h2_s, rg, c0);
        __syncthreads();
        {   // B3: f = h2 @ oW3 + ob3 ; y += (f - u) * dt ; emit out[t+1]
            float acc[8];
            const float bb = ob3[l];
#pragma unroll
            for (int i = 0; i < 8; ++i) acc[i] = bb;
#pragma unroll 2
            for (int k = 0; k < HH; k += 4) {
                const float w0 = oW3[(k + 0) * DD + l];
                const float w1 = oW3[(k + 1) * DD + l];
                const float w2 = oW3[(k + 2) * DD + l];
                const float w3 = oW3[(k + 3) * DD + l];
#pragma unroll
                for (int i = 0; i < 8; ++i) {
                    const float4 v = *(const float4*)&h2_s[(w * 8 + i) * HS + k];
                    float a = acc[i];
                    a = fmaf(v.x, w0, a);
                    a = fmaf(v.y, w1, a);
                    a = fmaf(v.z, w2, a);
                    a = fmaf(v.w, w3, a);
                    acc[i] = a;
                }
            }
#pragma unroll
            for (int i = 0; i < 8; ++i) {
                const int r = w * 8 + i;
                const float yv = y_s[r * AS + l];
                const float yn = yv + (acc[i] - ur[i]) * dt;
                y_s[r * AS + l] = yn;
                out[(size_t)(t + 1) * NB * DD + (size_t)(row0 + r) * DD + l] = yn;
            }
        }
        __syncthreads();
    }
}

extern "C" void kernel_launch(void* const* d_in, const int* in_sizes, int n_in,
                              void* d_out, int out_size, void* d_ws, size_t ws_size,
                              hipStream_t stream) {
    const float* y0    = (const float*)d_in[0];
    const float* tarr  = (const float*)d_in[1];
    const float* noise = (const float*)d_in[2];
    const float* oW1   = (const float*)d_in[3];
    const float* ob1   = (const float*)d_in[4];
    const float* oW2   = (const float*)d_in[5];
    const float* ob2   = (const float*)d_in[6];
    const float* oW3   = (const float*)d_in[7];
    const float* ob3   = (const float*)d_in[8];
    const float* amW1  = (const float*)d_in[9];
    const float* amb1  = (const float*)d_in[10];
    const float* amW2  = (const float*)d_in[11];
    const float* amb2  = (const float*)d_in[12];
    const float* amW3  = (const float*)d_in[13];
    const float* amb3  = (const float*)d_in[14];
    const float* asW1  = (const float*)d_in[15];
    const float* asb1  = (const float*)d_in[16];
    const float* asW2  = (const float*)d_in[17];
    const float* asb2  = (const float*)d_in[18];
    const float* asW3  = (const float*)d_in[19];
    const float* asb3  = (const float*)d_in[20];
    float* out = (float*)d_out;

    hipLaunchKernelGGL(ode_sac_kernel, dim3(NB / RR), dim3(NT), 0, stream,
                       y0, tarr, noise,
                       oW1, ob1, oW2, ob2, oW3, ob3,
                       amW1, amb1, amW2, amb2, amW3, amb3,
                       asW1, asb1, asW2, asb2, asW3, asb3,
                       out);
}

// Round 2
// 4146.535 us; speedup vs baseline: 5.1265x; 5.1265x over previous
//
#include <hip/hip_runtime.h>
#include <math.h>

#define NB 16384   // batch
#define DD 64      // state dim
#define HH 256     // ODE hidden
#define NSTEP 63   // T-1
#define RR 32      // rows per block
#define NT 256     // threads per block
#define AS 76      // word stride for 64-wide rows  (304 B, 16B-aligned)
#define HS 268     // word stride for 256-wide rows (1072 B, 16B-aligned)
// Row r of any LDS tile is stored at  r*stride + ((r>>3)&3)*4  words.
// Rows 8 apart (stride ≡ 0 mod 32 words) then land on banks {0,4,8,12} ->
// ds_read_b128 across the four 16-lane row-groups is conflict-free.

__device__ __forceinline__ float fast_tanh(float x) {
    float a = fabsf(x);
    float e = __expf(-2.0f * a);
    float r = (1.0f - e) / (1.0f + e);
    return copysignf(r, x);
}
__device__ __forceinline__ float fast_softplus(float x) {
    return fmaxf(x, 0.0f) + __logf(1.0f + __expf(-fabsf(x)));
}
__device__ __forceinline__ float clean_f(float x) {
    return isfinite(x) ? x : 0.0f;
}

// narrow layer: rows base..base+7 (pre-offset pointer), col l.
// in_b = in tile base already offset to this wave's row block (incl. bank shift)
__device__ __forceinline__ void mm64(const float* in_b,
                                     const float* __restrict__ W,
                                     const float* __restrict__ b,
                                     int l, float acc[8]) {
    const float bb = b[l];
#pragma unroll
    for (int i = 0; i < 8; ++i) acc[i] = bb;
#pragma unroll 4
    for (int k = 0; k < 64; k += 4) {
        const float w0 = W[(k + 0) * 64 + l];
        const float w1 = W[(k + 1) * 64 + l];
        const float w2 = W[(k + 2) * 64 + l];
        const float w3 = W[(k + 3) * 64 + l];
#pragma unroll
        for (int i = 0; i < 8; ++i) {
            const float4 v = *(const float4*)&in_b[i * AS + k];
            float a = acc[i];
            a = fmaf(v.x, w0, a);
            a = fmaf(v.y, w1, a);
            a = fmaf(v.z, w2, a);
            a = fmaf(v.w, w3, a);
            acc[i] = a;
        }
    }
}

// wide layer: rows (pre-offset base, stride istride), cols c0..c0+3, K deep.
// ACT: 0 = tanh, 1 = softplus. All accumulator indices compile-time (rule #20).
template <int K, int ACT>
__device__ __forceinline__ void mmwide(const float* in_b, int istride,
                                       const float* __restrict__ W,
                                       const float* __restrict__ b,
                                       float* out_b, int c0) {
    float4 acc[8];
    const float4 bias = *(const float4*)&b[c0];
#pragma unroll
    for (int i = 0; i < 8; ++i) acc[i] = bias;
#pragma unroll 2
    for (int k = 0; k < K; k += 4) {
        const float4 wa = *(const float4*)&W[(k + 0) * HH + c0];
        const float4 wb = *(const float4*)&W[(k + 1) * HH + c0];
        const float4 wc = *(const float4*)&W[(k + 2) * HH + c0];
        const float4 wd = *(const float4*)&W[(k + 3) * HH + c0];
#pragma unroll
        for (int i = 0; i < 8; ++i) {
            const float4 v = *(const float4*)&in_b[i * istride + k];
            float4 a = acc[i];
            a.x = fmaf(v.x, wa.x, a.x); a.y = fmaf(v.x, wa.y, a.y);
            a.z = fmaf(v.x, wa.z, a.z); a.w = fmaf(v.x, wa.w, a.w);
            a.x = fmaf(v.y, wb.x, a.x); a.y = fmaf(v.y, wb.y, a.y);
            a.z = fmaf(v.y, wb.z, a.z); a.w = fmaf(v.y, wb.w, a.w);
            a.x = fmaf(v.z, wc.x, a.x); a.y = fmaf(v.z, wc.y, a.y);
            a.z = fmaf(v.z, wc.z, a.z); a.w = fmaf(v.z, wc.w, a.w);
            a.x = fmaf(v.w, wd.x, a.x); a.y = fmaf(v.w, wd.y, a.y);
            a.z = fmaf(v.w, wd.z, a.z); a.w = fmaf(v.w, wd.w, a.w);
            acc[i] = a;
        }
    }
#pragma unroll
    for (int i = 0; i < 8; ++i) {
        float4 o = acc[i];
        if (ACT == 0) {
            o.x = fast_tanh(o.x); o.y = fast_tanh(o.y);
            o.z = fast_tanh(o.z); o.w = fast_tanh(o.w);
        } else {
            o.x = fast_softplus(o.x); o.y = fast_softplus(o.y);
            o.z = fast_softplus(o.z); o.w = fast_softplus(o.w);
        }
        *(float4*)&out_b[i * HS + c0] = o;
    }
}

extern "C" __global__ void __launch_bounds__(NT, 2)
ode_sac_kernel(const float* __restrict__ y0,
               const float* __restrict__ tarr,
               const float* __restrict__ noise,
               const float* __restrict__ oW1, const float* __restrict__ ob1,
               const float* __restrict__ oW2, const float* __restrict__ ob2,
               const float* __restrict__ oW3, const float* __restrict__ ob3,
               const float* __restrict__ amW1, const float* __restrict__ amb1,
               const float* __restrict__ amW2, const float* __restrict__ amb2,
               const float* __restrict__ amW3, const float* __restrict__ amb3,
               const float* __restrict__ asW1, const float* __restrict__ asb1,
               const float* __restrict__ asW2, const float* __restrict__ asb2,
               const float* __restrict__ asW3, const float* __restrict__ asb3,
               float* __restrict__ out) {
    __shared__ __align__(16) float lds[RR * AS + 2 * RR * HS];  // 78336 B -> 2 blocks/CU
    float* y_s  = lds;                 // [32] rows, stride AS
    float* h1_s = lds + RR * AS;       // [32] rows, stride HS (aliases a1m/a1s)
    float* h2_s = h1_s + RR * HS;      // [32] rows, stride HS (aliases a2m/a2s)
    // actor ping/pong buffers (64-wide, stride AS) carved out of h regions:
    float* a1m_s = h1_s;
    float* a1s_s = h1_s + RR * AS;     // 2*RR*AS = 4864 <= RR*HS = 8576  OK
    float* a2m_s = h2_s;
    float* a2s_s = h2_s + RR * AS;

    const int tid  = threadIdx.x;
    const int w    = tid >> 6;   // wave 0..3
    const int l    = tid & 63;   // lane
    const int row0 = blockIdx.x * RR;

    const int rg = l >> 4;                       // wide-layer row group 0..3
    const int c0 = (w * 16 + (l & 15)) * 4;      // wide-layer column base 0..252

    // pre-offset row-block bases (include bank shift ((r>>3)&3)*4 = group*4)
    const int wroffA = w * (8 * AS) + w * 4;     // this wave's rows, 64-wide tiles
    const int wroffH = w * (8 * HS) + w * 4;     // this wave's rows, 256-wide tiles
    const int groffA = rg * (8 * AS) + rg * 4;   // this lane-group's rows, 64-wide
    const int groffH = rg * (8 * HS) + rg * 4;   // this lane-group's rows, 256-wide

    const float dt = tarr[1] - tarr[0];

    // load y0 into LDS, emit out[0] = y0
#pragma unroll
    for (int i = 0; i < 8; ++i) {
        const int r = w * 8 + i;
        const float v = y0[(size_t)(row0 + r) * DD + l];
        y_s[wroffA + i * AS + l] = v;
        out[(size_t)(row0 + r) * DD + l] = v;
    }
    __syncthreads();

    for (int t = 0; t < NSTEP; ++t) {
        // prefetch this step's noise (consumed only in S3 -> latency hidden)
        float ep[8];
#pragma unroll
        for (int i = 0; i < 8; ++i)
            ep[i] = noise[(size_t)t * NB * DD + (size_t)(row0 + w * 8 + i) * DD + l];

        // ---- A1 & S1: first layers of both actor heads (read y, own rows) ----
        {
            float acc[8];
            mm64(y_s + wroffA, amW1, amb1, l, acc);
#pragma unroll
            for (int i = 0; i < 8; ++i) a1m_s[wroffA + i * AS + l] = fmaxf(acc[i], 0.0f);
            mm64(y_s + wroffA, asW1, asb1, l, acc);
#pragma unroll
            for (int i = 0; i < 8; ++i) a1s_s[wroffA + i * AS + l] = fmaxf(acc[i], 0.0f);
        }
        __syncthreads();
        // ---- A2 & S2 ----
        {
            float acc[8];
            mm64(a1m_s + wroffA, amW2, amb2, l, acc);
#pragma unroll
            for (int i = 0; i < 8; ++i) a2m_s[wroffA + i * AS + l] = fmaxf(acc[i], 0.0f);
            mm64(a1s_s + wroffA, asW2, asb2, l, acc);
#pragma unroll
            for (int i = 0; i < 8; ++i) a2s_s[wroffA + i * AS + l] = fmaxf(acc[i], 0.0f);
        }
        __syncthreads();

        float ur[8];
        // ---- A3 & S3: heads -> u (registers only) ----
        {
            float accm[8], accs[8];
            mm64(a2m_s + wroffA, amW3, amb3, l, accm);
            mm64(a2s_s + wroffA, asW3, asb3, l, accs);
#pragma unroll
            for (int i = 0; i < 8; ++i) {
                const float mean = clean_f(fast_tanh(accm[i]));
                const float ls   = clean_f(accs[i]);
                const float sd   = fast_softplus(ls);
                ur[i] = fast_tanh(mean + sd * ep[i]);
            }
        }
        // ---- B1: h1 = tanh(y @ oW1 + ob1)  (h1 aliases a1*, last read before bar) ----
        mmwide<DD, 0>(y_s + groffA, AS, oW1, ob1, h1_s + groffH, c0);
        __syncthreads();   // h1 complete; a2 reads (A3/S3) done before B2 overwrites h2
        // ---- B2: h2 = softplus(h1 @ oW2 + ob2) ----
        mmwide<HH, 1>(h1_s + groffH, HS, oW2, ob2, h2_s + groffH, c0);
        __syncthreads();
        // ---- B3: f = h2 @ oW3 + ob3 ; y += (f - u)*dt ; emit out[t+1] ----
        {
            float acc[8];
            const float bb = ob3[l];
#pragma unroll
            for (int i = 0; i < 8; ++i) acc[i] = bb;
#pragma unroll 2
            for (int k = 0; k < HH; k += 4) {
                const float w0 = oW3[(k + 0) * DD + l];
                const float w1 = oW3[(k + 1) * DD + l];
                const float w2 = oW3[(k + 2) * DD + l];
                const float w3 = oW3[(k + 3) * DD + l];
#pragma unroll
                for (int i = 0; i < 8; ++i) {
                    const float4 v = *(const float4*)&h2_s[wroffH + i * HS + k];
                    float a = acc[i];
                    a = fmaf(v.x, w0, a);
                    a = fmaf(v.y, w1, a);
                    a = fmaf(v.z, w2, a);
                    a = fmaf(v.w, w3, a);
                    acc[i] = a;
                }
            }
#pragma unroll
            for (int i = 0; i < 8; ++i) {
                const int r = w * 8 + i;
                const float yv = y_s[wroffA + i * AS + l];
                const float yn = yv + (acc[i] - ur[i]) * dt;
                y_s[wroffA + i * AS + l] = yn;   // own rows: next mm64 reads are same-wave
                out[(size_t)(t + 1) * NB * DD + (size_t)(row0 + r) * DD + l] = yn;
            }
        }
        __syncthreads();   // protects h2 (read by B3 cross-wave) & y (read by next B1)
    }
}

extern "C" void kernel_launch(void* const* d_in, const int* in_sizes, int n_in,
                              void* d_out, int out_size, void* d_ws, size_t ws_size,
                              hipStream_t stream) {
    const float* y0    = (const float*)d_in[0];
    const float* tarr  = (const float*)d_in[1];
    const float* noise = (const float*)d_in[2];
    const float* oW1   = (const float*)d_in[3];
    const float* ob1   = (const float*)d_in[4];
    const float* oW2   = (const float*)d_in[5];
    const float* ob2   = (const float*)d_in[6];
    const float* oW3   = (const float*)d_in[7];
    const float* ob3   = (const float*)d_in[8];
    const float* amW1  = (const float*)d_in[9];
    const float* amb1  = (const float*)d_in[10];
    const float* amW2  = (const float*)d_in[11];
    const float* amb2  = (const float*)d_in[12];
    const float* amW3  = (const float*)d_in[13];
    const float* amb3  = (const float*)d_in[14];
    const float* asW1  = (const float*)d_in[15];
    const float* asb1  = (const float*)d_in[16];
    const float* asW2  = (const float*)d_in[17];
    const float* asb2  = (const float*)d_in[18];
    const float* asW3  = (const float*)d_in[19];
    const float* asb3  = (const float*)d_in[20];
    float* out = (float*)d_out;

    hipLaunchKernelGGL(ode_sac_kernel, dim3(NB / RR), dim3(NT), 0, stream,
                       y0, tarr, noise,
                       oW1, ob1, oW2, ob2, oW3, ob3,
                       amW1, amb1, amW2, amb2, amW3, amb3,
                       asW1, asb1, asW2, asb2, asW3, asb3,
                       out);
}

// Round 4
// 3557.126 us; speedup vs baseline: 5.9759x; 1.1657x over previous
//
#include <hip/hip_runtime.h>
#include <hip/hip_bf16.h>
#include <math.h>

#define NB 16384
#define DD 64
#define HH 256
#define NSTEP 63
#define RB 64          // rows per block
#define NT 512         // 8 waves

#define SY 68          // u32 stride, packed y / actor bufs (≡4 mod 32)
#define SH 260         // u32 stride, packed h1/h2 (≡4 mod 32)

// dynamic LDS layout (u32 units)
#define OFF_Y   0
#define OFF_H1  (64 * SY)             // 4352
#define OFF_H2  (OFF_H1 + 64 * SH)    // 20992
#define LDS_U32 (OFF_H2 + 64 * SH)    // 37632
#define LDS_BYTES (LDS_U32 * 4)       // 150528 B -> 1 block/CU

// d_ws layout (ushort units) — every weight as hi+lo planes in B-frag order
#define O1H 0
#define O1L 16384
#define O2H 32768
#define O2L 98304
#define O3H 163840
#define O3L 180224
#define AM1H 196608
#define AM1L 200704
#define AM2H 204800
#define AM2L 208896
#define AM3H 212992
#define AM3L 217088
#define AS1H 221184
#define AS1L 225280
#define AS2H 229376
#define AS2L 233472
#define AS3H 237568
#define AS3L 241664
// total 245760 ushorts = 491520 B of d_ws

typedef __attribute__((ext_vector_type(8))) short s8v;          // 8 bf16
typedef __attribute__((ext_vector_type(4))) float f4v;          // MFMA acc
typedef __attribute__((ext_vector_type(4))) unsigned int u4v;

#define MFMA(a, b, c) __builtin_amdgcn_mfma_f32_16x16x32_bf16((a), (b), (c), 0, 0, 0)
// 3-term split product: A*B ≈ Ah*Bh + Ah*Bl + Al*Bh   (residual ~2^-18)
#define MM3(acc, ah, al, bh, bl)                                 \
    do {                                                         \
        acc = MFMA(ah, bh, acc);                                 \
        acc = MFMA(ah, bl, acc);                                 \
        acc = MFMA(al, bh, acc);                                 \
    } while (0)

__device__ __forceinline__ unsigned short f2b(float x) {
    return __builtin_bit_cast(unsigned short, (__bf16)x);
}
__device__ __forceinline__ float b2f(unsigned short u) {
    return __builtin_bit_cast(float, (unsigned int)u << 16);
}
__device__ __forceinline__ unsigned int packsplit(float x) {
    const unsigned short hi = f2b(x);
    const unsigned short lo = f2b(x - b2f(hi));
    return (unsigned int)hi | ((unsigned int)lo << 16);
}
__device__ __forceinline__ float fast_tanh(float x) {
    float e = __expf(-2.0f * fabsf(x));
    float r = __fdividef(1.0f - e, 1.0f + e);
    return copysignf(r, x);
}
__device__ __forceinline__ float fast_softplus(float x) {
    return fmaxf(x, 0.0f) + __logf(1.0f + __expf(-fabsf(x)));
}
__device__ __forceinline__ float clean_f(float x) { return isfinite(x) ? x : 0.0f; }
__device__ __forceinline__ f4v splat4(float b) { f4v v = {b, b, b, b}; return v; }

// read 8 packed u32 (hi|lo), unpack to hi/lo bf16 A-fragments
__device__ __forceinline__ void ldsPK(const unsigned int* p, s8v* hi, s8v* lo) {
    const u4v q0 = *(const u4v*)p;
    const u4v q1 = *(const u4v*)(p + 4);
    union { unsigned int u[4]; s8v v; } H, L;
    H.u[0] = __builtin_amdgcn_perm(q0[1], q0[0], 0x05040100);
    L.u[0] = __builtin_amdgcn_perm(q0[1], q0[0], 0x07060302);
    H.u[1] = __builtin_amdgcn_perm(q0[3], q0[2], 0x05040100);
    L.u[1] = __builtin_amdgcn_perm(q0[3], q0[2], 0x07060302);
    H.u[2] = __builtin_amdgcn_perm(q1[1], q1[0], 0x05040100);
    L.u[2] = __builtin_amdgcn_perm(q1[1], q1[0], 0x07060302);
    H.u[3] = __builtin_amdgcn_perm(q1[3], q1[2], 0x05040100);
    L.u[3] = __builtin_amdgcn_perm(q1[3], q1[2], 0x07060302);
    *hi = H.v; *lo = L.v;
}

// swizzle W[K x N] f32 into B-fragment order, split bf16 hi+lo
__global__ void prep_kernel(const float* __restrict__ W, int K, int N,
                            unsigned short* __restrict__ hi,
                            unsigned short* __restrict__ lo) {
    const int l = threadIdx.x;            // 64
    const int kcN = K >> 5;
    const int nt = blockIdx.x / kcN;
    const int kc = blockIdx.x % kcN;
    const int col = nt * 16 + (l & 15);
    const int k0 = kc * 32 + ((l >> 4) << 3);
    const size_t base = ((size_t)(nt * kcN + kc) * 64 + l) * 8;
#pragma unroll
    for (int b = 0; b < 8; ++b) {
        float wv = W[(size_t)(k0 + b) * N + col];
        unsigned short h = f2b(wv);
        hi[base + b] = h;
        lo[base + b] = f2b(wv - b2f(h));
    }
}

extern "C" __global__ void __launch_bounds__(NT, 2)
ode_sac_kernel(const float* __restrict__ y0,
               const float* __restrict__ tarr,
               const float* __restrict__ noise,
               const float* __restrict__ ob1, const float* __restrict__ ob2,
               const float* __restrict__ ob3,
               const float* __restrict__ amb1, const float* __restrict__ amb2,
               const float* __restrict__ amb3,
               const float* __restrict__ asb1, const float* __restrict__ asb2,
               const float* __restrict__ asb3,
               const unsigned short* __restrict__ ws,
               float* __restrict__ out) {
    extern __shared__ unsigned int smem[];
    unsigned int* y_pk  = smem + OFF_Y;    // [64 rows][stride SY]
    unsigned int* h1_pk = smem + OFF_H1;   // [64][SH]
    unsigned int* h2_pk = smem + OFF_H2;   // [64][SH]
    unsigned int* a1m = h1_pk;             // [64][SY] carved from h1
    unsigned int* a1s = h1_pk + 64 * SY;
    unsigned int* a2m = h2_pk;             // carved from h2
    unsigned int* a2s = h2_pk + 64 * SY;

    const int tid = threadIdx.x;
    const int w  = tid >> 6;       // wave 0..7
    const int l  = tid & 63;
    const int lm = l & 15;
    const int lg = l >> 4;
    const int wm = w >> 2;         // M-half: rows wm*32..+31
    const int wn = w & 3;          // N-quarter (wide) / n-tile (narrow)
    const int row0 = blockIdx.x * RB;
    const int cN = wn * 16 + lm;   // narrow-layer / B3 / ownership column

    const float dt = tarr[1] - tarr[0];

    // fragment plane pointers
    const s8v* o1h = (const s8v*)(ws + O1H); const s8v* o1l = (const s8v*)(ws + O1L);
    const s8v* o2h = (const s8v*)(ws + O2H); const s8v* o2l = (const s8v*)(ws + O2L);
    const s8v* o3h = (const s8v*)(ws + O3H); const s8v* o3l = (const s8v*)(ws + O3L);
    const s8v* am1h = (const s8v*)(ws + AM1H); const s8v* am1l = (const s8v*)(ws + AM1L);
    const s8v* am2h = (const s8v*)(ws + AM2H); const s8v* am2l = (const s8v*)(ws + AM2L);
    const s8v* am3h = (const s8v*)(ws + AM3H); const s8v* am3l = (const s8v*)(ws + AM3L);
    const s8v* as1h = (const s8v*)(ws + AS1H); const s8v* as1l = (const s8v*)(ws + AS1L);
    const s8v* as2h = (const s8v*)(ws + AS2H); const s8v* as2l = (const s8v*)(ws + AS2L);
    const s8v* as3h = (const s8v*)(ws + AS3H); const s8v* as3l = (const s8v*)(ws + AS3L);

    // biases
    const float b_am1 = amb1[cN], b_am2 = amb2[cN], b_am3 = amb3[cN];
    const float b_as1 = asb1[cN], b_as2 = asb2[cN], b_as3 = asb3[cN];
    const float b_o3  = ob3[cN];
    float b_o1v[4], b_o2v[4];
#pragma unroll
    for (int nt = 0; nt < 4; ++nt) {
        const int col = wn * 64 + nt * 16 + lm;
        b_o1v[nt] = ob1[col];
        b_o2v[nt] = ob2[col];
    }

    // y state in registers: element (mt,r) at row wm*32+mt*16+lg*4+r, col cN
    float ys[2][4];
#pragma unroll
    for (int mt = 0; mt < 2; ++mt)
#pragma unroll
        for (int r = 0; r < 4; ++r) {
            const int row = wm * 32 + mt * 16 + lg * 4 + r;
            const float v = y0[(size_t)(row0 + row) * DD + cN];
            ys[mt][r] = v;
            y_pk[row * SY + cN] = packsplit(v);
            out[(size_t)(row0 + row) * DD + cN] = v;
        }
    __syncthreads();

    for (int t = 0; t < NSTEP; ++t) {
        // noise prefetch (used in P3)
        float ep[2][4];
#pragma unroll
        for (int mt = 0; mt < 2; ++mt)
#pragma unroll
            for (int r = 0; r < 4; ++r) {
                const int row = wm * 32 + mt * 16 + lg * 4 + r;
                ep[mt][r] = noise[(size_t)t * NB * DD + (size_t)(row0 + row) * DD + cN];
            }

        // ---------- P1: A1 & S1 = relu(y @ W1 + b), 3-term ----------
        {
            f4v am[2] = {splat4(b_am1), splat4(b_am1)};
            f4v as[2] = {splat4(b_as1), splat4(b_as1)};
#pragma unroll
            for (int kc = 0; kc < 2; ++kc) {
                s8v yh[2], yl[2];
#pragma unroll
                for (int mt = 0; mt < 2; ++mt)
                    ldsPK(&y_pk[(wm * 32 + mt * 16 + lm) * SY + kc * 32 + lg * 8],
                          &yh[mt], &yl[mt]);
                const int fb = (wn * 2 + kc) * 64 + l;
                const s8v bmh = am1h[fb], bml = am1l[fb];
                const s8v bsh = as1h[fb], bsl = as1l[fb];
#pragma unroll
                for (int mt = 0; mt < 2; ++mt) {
                    MM3(am[mt], yh[mt], yl[mt], bmh, bml);
                    MM3(as[mt], yh[mt], yl[mt], bsh, bsl);
                }
            }
#pragma unroll
            for (int mt = 0; mt < 2; ++mt)
#pragma unroll
                for (int r = 0; r < 4; ++r) {
                    const int row = wm * 32 + mt * 16 + lg * 4 + r;
                    a1m[row * SY + cN] = packsplit(fmaxf(am[mt][r], 0.0f));
                    a1s[row * SY + cN] = packsplit(fmaxf(as[mt][r], 0.0f));
                }
        }
        __syncthreads();

        // ---------- P2: A2 & S2 ----------
        {
            f4v am[2] = {splat4(b_am2), splat4(b_am2)};
            f4v as[2] = {splat4(b_as2), splat4(b_as2)};
#pragma unroll
            for (int kc = 0; kc < 2; ++kc) {
                const int k0 = kc * 32 + lg * 8;
                s8v mh[2], ml[2], sh[2], sl[2];
#pragma unroll
                for (int mt = 0; mt < 2; ++mt) {
                    const int rr = (wm * 32 + mt * 16 + lm) * SY + k0;
                    ldsPK(&a1m[rr], &mh[mt], &ml[mt]);
                    ldsPK(&a1s[rr], &sh[mt], &sl[mt]);
                }
                const int fb = (wn * 2 + kc) * 64 + l;
                const s8v bmh = am2h[fb], bml = am2l[fb];
                const s8v bsh = as2h[fb], bsl = as2l[fb];
#pragma unroll
                for (int mt = 0; mt < 2; ++mt) {
                    MM3(am[mt], mh[mt], ml[mt], bmh, bml);
                    MM3(as[mt], sh[mt], sl[mt], bsh, bsl);
                }
            }
#pragma unroll
            for (int mt = 0; mt < 2; ++mt)
#pragma unroll
                for (int r = 0; r < 4; ++r) {
                    const int row = wm * 32 + mt * 16 + lg * 4 + r;
                    a2m[row * SY + cN] = packsplit(fmaxf(am[mt][r], 0.0f));
                    a2s[row * SY + cN] = packsplit(fmaxf(as[mt][r], 0.0f));
                }
        }
        __syncthreads();

        // ---------- P3: A3 & S3 -> u (regs);  B1 -> h1 ----------
        float u[2][4];
        {
            f4v m3[2] = {splat4(b_am3), splat4(b_am3)};
            f4v s3[2] = {splat4(b_as3), splat4(b_as3)};
#pragma unroll
            for (int kc = 0; kc < 2; ++kc) {
                const int k0 = kc * 32 + lg * 8;
                s8v mh[2], ml[2], sh[2], sl[2];
#pragma unroll
                for (int mt = 0; mt < 2; ++mt) {
                    const int rr = (wm * 32 + mt * 16 + lm) * SY + k0;
                    ldsPK(&a2m[rr], &mh[mt], &ml[mt]);
                    ldsPK(&a2s[rr], &sh[mt], &sl[mt]);
                }
                const int fb = (wn * 2 + kc) * 64 + l;
                const s8v bmh = am3h[fb], bml = am3l[fb];
                const s8v bsh = as3h[fb], bsl = as3l[fb];
#pragma unroll
                for (int mt = 0; mt < 2; ++mt) {
                    MM3(m3[mt], mh[mt], ml[mt], bmh, bml);
                    MM3(s3[mt], sh[mt], sl[mt], bsh, bsl);
                }
            }
#pragma unroll
            for (int mt = 0; mt < 2; ++mt)
#pragma unroll
                for (int r = 0; r < 4; ++r) {
                    const float mean = clean_f(fast_tanh(m3[mt][r]));
                    const float ls   = clean_f(s3[mt][r]);
                    const float sd   = fast_softplus(ls);
                    u[mt][r] = fast_tanh(mean + sd * ep[mt][r]);
                }
        }
        {   // B1: h1 = tanh(y @ oW1 + ob1)
            f4v acc[2][4];
#pragma unroll
            for (int mt = 0; mt < 2; ++mt)
#pragma unroll
                for (int nt = 0; nt < 4; ++nt) acc[mt][nt] = splat4(b_o1v[nt]);
#pragma unroll
            for (int kc = 0; kc < 2; ++kc) {
                s8v yh[2], yl[2];
#pragma unroll
                for (int mt = 0; mt < 2; ++mt)
                    ldsPK(&y_pk[(wm * 32 + mt * 16 + lm) * SY + kc * 32 + lg * 8],
                          &yh[mt], &yl[mt]);
#pragma unroll
                for (int nt = 0; nt < 4; ++nt) {
                    const int fb = (((wn * 4 + nt) * 2) + kc) * 64 + l;
                    const s8v bh = o1h[fb], bl = o1l[fb];
#pragma unroll
                    for (int mt = 0; mt < 2; ++mt)
                        MM3(acc[mt][nt], yh[mt], yl[mt], bh, bl);
                }
            }
#pragma unroll
            for (int mt = 0; mt < 2; ++mt)
#pragma unroll
                for (int nt = 0; nt < 4; ++nt)
#pragma unroll
                    for (int r = 0; r < 4; ++r) {
                        const int row = wm * 32 + mt * 16 + lg * 4 + r;
                        const int col = wn * 64 + nt * 16 + lm;
                        h1_pk[row * SH + col] = packsplit(fast_tanh(acc[mt][nt][r]));
                    }
        }
        __syncthreads();

        // ---------- P4: B2 = softplus(h1 @ oW2 + ob2) ----------
        {
            f4v acc[2][4];
#pragma unroll
            for (int mt = 0; mt < 2; ++mt)
#pragma unroll
                for (int nt = 0; nt < 4; ++nt) acc[mt][nt] = splat4(b_o2v[nt]);
#pragma unroll
            for (int kc = 0; kc < 8; ++kc) {
                s8v ah[2], al[2];
#pragma unroll
                for (int mt = 0; mt < 2; ++mt)
                    ldsPK(&h1_pk[(wm * 32 + mt * 16 + lm) * SH + kc * 32 + lg * 8],
                          &ah[mt], &al[mt]);
#pragma unroll
                for (int nt = 0; nt < 4; ++nt) {
                    const int fb = (((wn * 4 + nt) * 8) + kc) * 64 + l;
                    const s8v bh = o2h[fb], bl = o2l[fb];
#pragma unroll
                    for (int mt = 0; mt < 2; ++mt)
                        MM3(acc[mt][nt], ah[mt], al[mt], bh, bl);
                }
            }
#pragma unroll
            for (int mt = 0; mt < 2; ++mt)
#pragma unroll
                for (int nt = 0; nt < 4; ++nt)
#pragma unroll
                    for (int r = 0; r < 4; ++r) {
                        const int row = wm * 32 + mt * 16 + lg * 4 + r;
                        const int col = wn * 64 + nt * 16 + lm;
                        h2_pk[row * SH + col] = packsplit(fast_softplus(acc[mt][nt][r]));
                    }
        }
        __syncthreads();

        // ---------- P5: B3 = h2 @ oW3 + ob3 ; y += (f - u)*dt ----------
        {
            f4v f3[2] = {splat4(b_o3), splat4(b_o3)};
#pragma unroll
            for (int kc = 0; kc < 8; ++kc) {
                s8v ah[2], al[2];
#pragma unroll
                for (int mt = 0; mt < 2; ++mt)
                    ldsPK(&h2_pk[(wm * 32 + mt * 16 + lm) * SH + kc * 32 + lg * 8],
                          &ah[mt], &al[mt]);
                const int fb = (wn * 8 + kc) * 64 + l;
                const s8v bh = o3h[fb], bl = o3l[fb];
#pragma unroll
                for (int mt = 0; mt < 2; ++mt)
                    MM3(f3[mt], ah[mt], al[mt], bh, bl);
            }
#pragma unroll
            for (int mt = 0; mt < 2; ++mt)
#pragma unroll
                for (int r = 0; r < 4; ++r) {
                    const int row = wm * 32 + mt * 16 + lg * 4 + r;
                    const float yn = ys[mt][r] + (f3[mt][r] - u[mt][r]) * dt;
                    ys[mt][r] = yn;
                    y_pk[row * SY + cN] = packsplit(yn);
                    out[(size_t)(t + 1) * NB * DD + (size_t)(row0 + row) * DD + cN] = yn;
                }
        }
        __syncthreads();
    }
}

extern "C" void kernel_launch(void* const* d_in, const int* in_sizes, int n_in,
                              void* d_out, int out_size, void* d_ws, size_t ws_size,
                              hipStream_t stream) {
    const float* y0    = (const float*)d_in[0];
    const float* tarr  = (const float*)d_in[1];
    const float* noise = (const float*)d_in[2];
    const float* oW1 = (const float*)d_in[3];  const float* ob1 = (const float*)d_in[4];
    const float* oW2 = (const float*)d_in[5];  const float* ob2 = (const float*)d_in[6];
    const float* oW3 = (const float*)d_in[7];  const float* ob3 = (const float*)d_in[8];
    const float* amW1 = (const float*)d_in[9];  const float* amb1 = (const float*)d_in[10];
    const float* amW2 = (const float*)d_in[11]; const float* amb2 = (const float*)d_in[12];
    const float* amW3 = (const float*)d_in[13]; const float* amb3 = (const float*)d_in[14];
    const float* asW1 = (const float*)d_in[15]; const float* asb1 = (const float*)d_in[16];
    const float* asW2 = (const float*)d_in[17]; const float* asb2 = (const float*)d_in[18];
    const float* asW3 = (const float*)d_in[19]; const float* asb3 = (const float*)d_in[20];
    float* out = (float*)d_out;
    unsigned short* wsp = (unsigned short*)d_ws;

    // weight swizzle + hi/lo split (step-invariant)
    hipLaunchKernelGGL(prep_kernel, dim3(16 * 2), dim3(64), 0, stream, oW1, 64, 256, wsp + O1H, wsp + O1L);
    hipLaunchKernelGGL(prep_kernel, dim3(16 * 8), dim3(64), 0, stream, oW2, 256, 256, wsp + O2H, wsp + O2L);
    hipLaunchKernelGGL(prep_kernel, dim3(4 * 8),  dim3(64), 0, stream, oW3, 256, 64, wsp + O3H, wsp + O3L);
    hipLaunchKernelGGL(prep_kernel, dim3(4 * 2),  dim3(64), 0, stream, amW1, 64, 64, wsp + AM1H, wsp + AM1L);
    hipLaunchKernelGGL(prep_kernel, dim3(4 * 2),  dim3(64), 0, stream, amW2, 64, 64, wsp + AM2H, wsp + AM2L);
    hipLaunchKernelGGL(prep_kernel, dim3(4 * 2),  dim3(64), 0, stream, amW3, 64, 64, wsp + AM3H, wsp + AM3L);
    hipLaunchKernelGGL(prep_kernel, dim3(4 * 2),  dim3(64), 0, stream, asW1, 64, 64, wsp + AS1H, wsp + AS1L);
    hipLaunchKernelGGL(prep_kernel, dim3(4 * 2),  dim3(64), 0, stream, asW2, 64, 64, wsp + AS2H, wsp + AS2L);
    hipLaunchKernelGGL(prep_kernel, dim3(4 * 2),  dim3(64), 0, stream, asW3, 64, 64, wsp + AS3H, wsp + AS3L);

    static int attr_set = 0;
    (void)attr_set;  // hipFuncSetAttribute is idempotent & capture-safe; call every time
    hipFuncSetAttribute((const void*)ode_sac_kernel,
                        hipFuncAttributeMaxDynamicSharedMemorySize, LDS_BYTES);

    hipLaunchKernelGGL(ode_sac_kernel, dim3(NB / RB), dim3(NT), LDS_BYTES, stream,
                       y0, tarr, noise,
                       ob1, ob2, ob3, amb1, amb2, amb3, asb1, asb2, asb3,
                       wsp, out);
}

// Round 5
// 2433.582 us; speedup vs baseline: 8.7349x; 1.4617x over previous
//
#include <hip/hip_runtime.h>
#include <hip/hip_bf16.h>
#include <math.h>

#define NB 16384
#define DD 64
#define HH 256
#define NSTEP 63
#define RB 64          // rows per block
#define NT 512         // 8 waves

#define SY 68          // u32 stride, packed y / actor bufs (≡4 mod 32)
#define SH 260         // u32 stride, packed h1/h2 (≡4 mod 32)

// dynamic LDS layout (u32 units)
#define OFF_Y   0
#define OFF_H1  (64 * SY)             // 4352
#define OFF_H2  (OFF_H1 + 64 * SH)    // 20992
#define LDS_U32 (OFF_H2 + 64 * SH)    // 37632
#define LDS_BYTES (LDS_U32 * 4)       // 150528 B -> 1 block/CU

// d_ws layout (ushort units) — every weight as hi+lo planes in B-frag order
#define O1H 0
#define O1L 16384
#define O2H 32768
#define O2L 98304
#define O3H 163840
#define O3L 180224
#define AM1H 196608
#define AM1L 200704
#define AM2H 204800
#define AM2L 208896
#define AM3H 212992
#define AM3L 217088
#define AS1H 221184
#define AS1L 225280
#define AS2H 229376
#define AS2L 233472
#define AS3H 237568
#define AS3L 241664

typedef __attribute__((ext_vector_type(8))) short s8v;          // 8 bf16
typedef __attribute__((ext_vector_type(4))) float f4v;          // MFMA acc
typedef __attribute__((ext_vector_type(4))) unsigned int u4v;

#define MFMA(a, b, c) __builtin_amdgcn_mfma_f32_16x16x32_bf16((a), (b), (c), 0, 0, 0)
// 3-term split product: A*B ≈ Ah*Bh + Ah*Bl + Al*Bh   (residual ~2^-18)
#define MM3(acc, ah, al, bh, bl)                                 \
    do {                                                         \
        acc = MFMA(ah, bh, acc);                                 \
        acc = MFMA(ah, bl, acc);                                 \
        acc = MFMA(al, bh, acc);                                 \
    } while (0)

__device__ __forceinline__ unsigned short f2b(float x) {
    return __builtin_bit_cast(unsigned short, (__bf16)x);
}
__device__ __forceinline__ float b2f(unsigned short u) {
    return __builtin_bit_cast(float, (unsigned int)u << 16);
}
__device__ __forceinline__ unsigned int packsplit(float x) {
    const unsigned short hi = f2b(x);
    const unsigned short lo = f2b(x - b2f(hi));
    return (unsigned int)hi | ((unsigned int)lo << 16);
}
__device__ __forceinline__ float unpacksum(unsigned int pk) {
    return b2f((unsigned short)(pk & 0xFFFFu)) + b2f((unsigned short)(pk >> 16));
}
__device__ __forceinline__ float fast_tanh(float x) {
    float e = __expf(-2.0f * fabsf(x));
    float r = __fdividef(1.0f - e, 1.0f + e);
    return copysignf(r, x);
}
__device__ __forceinline__ float fast_softplus(float x) {
    return fmaxf(x, 0.0f) + __logf(1.0f + __expf(-fabsf(x)));
}
__device__ __forceinline__ float clean_f(float x) { return isfinite(x) ? x : 0.0f; }
__device__ __forceinline__ f4v splat4(float b) { f4v v = {b, b, b, b}; return v; }

// read 8 packed u32 (hi|lo), unpack to hi/lo bf16 A-fragments
__device__ __forceinline__ void ldsPK(const unsigned int* p, s8v* hi, s8v* lo) {
    const u4v q0 = *(const u4v*)p;
    const u4v q1 = *(const u4v*)(p + 4);
    union { unsigned int u[4]; s8v v; } H, L;
    H.u[0] = __builtin_amdgcn_perm(q0[1], q0[0], 0x05040100);
    L.u[0] = __builtin_amdgcn_perm(q0[1], q0[0], 0x07060302);
    H.u[1] = __builtin_amdgcn_perm(q0[3], q0[2], 0x05040100);
    L.u[1] = __builtin_amdgcn_perm(q0[3], q0[2], 0x07060302);
    H.u[2] = __builtin_amdgcn_perm(q1[1], q1[0], 0x05040100);
    L.u[2] = __builtin_amdgcn_perm(q1[1], q1[0], 0x07060302);
    H.u[3] = __builtin_amdgcn_perm(q1[3], q1[2], 0x05040100);
    L.u[3] = __builtin_amdgcn_perm(q1[3], q1[2], 0x07060302);
    *hi = H.v; *lo = L.v;
}

// swizzle W[K x N] f32 into B-fragment order, split bf16 hi+lo
__global__ void prep_kernel(const float* __restrict__ W, int K, int N,
                            unsigned short* __restrict__ hi,
                            unsigned short* __restrict__ lo) {
    const int l = threadIdx.x;            // 64
    const int kcN = K >> 5;
    const int nt = blockIdx.x / kcN;
    const int kc = blockIdx.x % kcN;
    const int col = nt * 16 + (l & 15);
    const int k0 = kc * 32 + ((l >> 4) << 3);
    const size_t base = ((size_t)(nt * kcN + kc) * 64 + l) * 8;
#pragma unroll
    for (int b = 0; b < 8; ++b) {
        float wv = W[(size_t)(k0 + b) * N + col];
        unsigned short h = f2b(wv);
        hi[base + b] = h;
        lo[base + b] = f2b(wv - b2f(h));
    }
}

extern "C" __global__ void __launch_bounds__(NT, 2)
ode_sac_kernel(const float* __restrict__ y0,
               const float* __restrict__ tarr,
               const float* __restrict__ noise,
               const float* __restrict__ ob1, const float* __restrict__ ob2,
               const float* __restrict__ ob3,
               const float* __restrict__ amb1, const float* __restrict__ amb2,
               const float* __restrict__ amb3,
               const float* __restrict__ asb1, const float* __restrict__ asb2,
               const float* __restrict__ asb3,
               const unsigned short* __restrict__ ws,
               float* __restrict__ out) {
    extern __shared__ unsigned int smem[];
    unsigned int* y_pk  = smem + OFF_Y;    // [64 rows][stride SY]
    unsigned int* h1_pk = smem + OFF_H1;   // [64][SH]
    unsigned int* h2_pk = smem + OFF_H2;   // [64][SH]
    unsigned int* a1m = h1_pk;             // [64][SY] carved from h1
    unsigned int* a1s = h1_pk + 64 * SY;
    unsigned int* a2m = h2_pk;             // carved from h2
    unsigned int* a2s = h2_pk + 64 * SY;

    const int tid = threadIdx.x;
    const int w  = tid >> 6;       // wave 0..7
    const int l  = tid & 63;
    const int lm = l & 15;
    const int lg = l >> 4;
    const int wm = w >> 2;         // M-half (narrow layers): rows wm*32..+31
    const int wn = w & 3;          // n-tile (narrow layers)
    const int row0 = blockIdx.x * RB;
    const int cN = wn * 16 + lm;   // narrow-layer / B3 ownership column

    const float dt = tarr[1] - tarr[0];

    // fragment plane pointers
    const s8v* o1h = (const s8v*)(ws + O1H); const s8v* o1l = (const s8v*)(ws + O1L);
    const s8v* o2hp = (const s8v*)(ws + O2H); const s8v* o2lp = (const s8v*)(ws + O2L);
    const s8v* o3h = (const s8v*)(ws + O3H); const s8v* o3l = (const s8v*)(ws + O3L);
    const s8v* am1h = (const s8v*)(ws + AM1H); const s8v* am1l = (const s8v*)(ws + AM1L);
    const s8v* am2h = (const s8v*)(ws + AM2H); const s8v* am2l = (const s8v*)(ws + AM2L);
    const s8v* am3h = (const s8v*)(ws + AM3H); const s8v* am3l = (const s8v*)(ws + AM3L);
    const s8v* as1h = (const s8v*)(ws + AS1H); const s8v* as1l = (const s8v*)(ws + AS1L);
    const s8v* as2h = (const s8v*)(ws + AS2H); const s8v* as2l = (const s8v*)(ws + AS2L);
    const s8v* as3h = (const s8v*)(ws + AS3H); const s8v* as3l = (const s8v*)(ws + AS3L);

    // ---- persistent oW2 slice: col-tiles {2w, 2w+1}, all 8 k-chunks ----
    s8v o2hr[2][8], o2lr[2][8];
#pragma unroll
    for (int ntl = 0; ntl < 2; ++ntl)
#pragma unroll
        for (int kc = 0; kc < 8; ++kc) {
            const int fb = ((w * 2 + ntl) * 8 + kc) * 64 + l;
            o2hr[ntl][kc] = o2hp[fb];
            o2lr[ntl][kc] = o2lp[fb];
        }

    // biases
    const float b_am1 = amb1[cN], b_am2 = amb2[cN], b_am3 = amb3[cN];
    const float b_as1 = asb1[cN], b_as2 = asb2[cN], b_as3 = asb3[cN];
    const float b_o3  = ob3[cN];
    const float b_o2a = ob2[(w * 2) * 16 + lm];
    const float b_o2b = ob2[(w * 2 + 1) * 16 + lm];
    float b_o1v[4];
#pragma unroll
    for (int nt = 0; nt < 4; ++nt) b_o1v[nt] = ob1[wn * 64 + nt * 16 + lm];

    // y state in registers (exact f32): element (mt,r) at row wm*32+mt*16+lg*4+r, col cN
    float ys[2][4];
#pragma unroll
    for (int mt = 0; mt < 2; ++mt)
#pragma unroll
        for (int r = 0; r < 4; ++r) {
            const int row = wm * 32 + mt * 16 + lg * 4 + r;
            const float v = y0[(size_t)(row0 + row) * DD + cN];
            ys[mt][r] = v;
            y_pk[row * SY + cN] = packsplit(v);
        }
    __syncthreads();

    // out[0] = y0, coalesced via y_pk (hi+lo, err ~2e-3)
    {
        const int orow = tid >> 3;
        const int oc0 = (tid & 7) * 8;
        const unsigned int* p = &y_pk[orow * SY + oc0];
        float v[8];
#pragma unroll
        for (int j = 0; j < 8; ++j) v[j] = unpacksum(p[j]);
        float4* dst = (float4*)&out[(size_t)(row0 + orow) * DD + oc0];
        dst[0] = make_float4(v[0], v[1], v[2], v[3]);
        dst[1] = make_float4(v[4], v[5], v[6], v[7]);
    }

    for (int t = 0; t < NSTEP; ++t) {
        // noise prefetch (used in P3)
        float ep[2][4];
#pragma unroll
        for (int mt = 0; mt < 2; ++mt)
#pragma unroll
            for (int r = 0; r < 4; ++r) {
                const int row = wm * 32 + mt * 16 + lg * 4 + r;
                ep[mt][r] = noise[(size_t)t * NB * DD + (size_t)(row0 + row) * DD + cN];
            }

        // ---------- P1: A1 & S1 = relu(y @ W1 + b), 3-term ----------
        {
            f4v am[2] = {splat4(b_am1), splat4(b_am1)};
            f4v as[2] = {splat4(b_as1), splat4(b_as1)};
#pragma unroll
            for (int kc = 0; kc < 2; ++kc) {
                s8v yh[2], yl[2];
#pragma unroll
                for (int mt = 0; mt < 2; ++mt)
                    ldsPK(&y_pk[(wm * 32 + mt * 16 + lm) * SY + kc * 32 + lg * 8],
                          &yh[mt], &yl[mt]);
                const int fb = (wn * 2 + kc) * 64 + l;
                const s8v bmh = am1h[fb], bml = am1l[fb];
                const s8v bsh = as1h[fb], bsl = as1l[fb];
#pragma unroll
                for (int mt = 0; mt < 2; ++mt) {
                    MM3(am[mt], yh[mt], yl[mt], bmh, bml);
                    MM3(as[mt], yh[mt], yl[mt], bsh, bsl);
                }
            }
#pragma unroll
            for (int mt = 0; mt < 2; ++mt)
#pragma unroll
                for (int r = 0; r < 4; ++r) {
                    const int row = wm * 32 + mt * 16 + lg * 4 + r;
                    a1m[row * SY + cN] = packsplit(fmaxf(am[mt][r], 0.0f));
                    a1s[row * SY + cN] = packsplit(fmaxf(as[mt][r], 0.0f));
                }
        }
        __syncthreads();

        // ---------- P2: A2 & S2 ----------
        {
            f4v am[2] = {splat4(b_am2), splat4(b_am2)};
            f4v as[2] = {splat4(b_as2), splat4(b_as2)};
#pragma unroll
            for (int kc = 0; kc < 2; ++kc) {
                const int k0 = kc * 32 + lg * 8;
                s8v mh[2], ml[2], sh[2], sl[2];
#pragma unroll
                for (int mt = 0; mt < 2; ++mt) {
                    const int rr = (wm * 32 + mt * 16 + lm) * SY + k0;
                    ldsPK(&a1m[rr], &mh[mt], &ml[mt]);
                    ldsPK(&a1s[rr], &sh[mt], &sl[mt]);
                }
                const int fb = (wn * 2 + kc) * 64 + l;
                const s8v bmh = am2h[fb], bml = am2l[fb];
                const s8v bsh = as2h[fb], bsl = as2l[fb];
#pragma unroll
                for (int mt = 0; mt < 2; ++mt) {
                    MM3(am[mt], mh[mt], ml[mt], bmh, bml);
                    MM3(as[mt], sh[mt], sl[mt], bsh, bsl);
                }
            }
#pragma unroll
            for (int mt = 0; mt < 2; ++mt)
#pragma unroll
                for (int r = 0; r < 4; ++r) {
                    const int row = wm * 32 + mt * 16 + lg * 4 + r;
                    a2m[row * SY + cN] = packsplit(fmaxf(am[mt][r], 0.0f));
                    a2s[row * SY + cN] = packsplit(fmaxf(as[mt][r], 0.0f));
                }
        }
        __syncthreads();

        // ---------- P3: A3 & S3 -> u (regs);  B1 -> h1 ----------
        float u[2][4];
        {
            f4v m3[2] = {splat4(b_am3), splat4(b_am3)};
            f4v s3[2] = {splat4(b_as3), splat4(b_as3)};
#pragma unroll
            for (int kc = 0; kc < 2; ++kc) {
                const int k0 = kc * 32 + lg * 8;
                s8v mh[2], ml[2], sh[2], sl[2];
#pragma unroll
                for (int mt = 0; mt < 2; ++mt) {
                    const int rr = (wm * 32 + mt * 16 + lm) * SY + k0;
                    ldsPK(&a2m[rr], &mh[mt], &ml[mt]);
                    ldsPK(&a2s[rr], &sh[mt], &sl[mt]);
                }
                const int fb = (wn * 2 + kc) * 64 + l;
                const s8v bmh = am3h[fb], bml = am3l[fb];
                const s8v bsh = as3h[fb], bsl = as3l[fb];
#pragma unroll
                for (int mt = 0; mt < 2; ++mt) {
                    MM3(m3[mt], mh[mt], ml[mt], bmh, bml);
                    MM3(s3[mt], sh[mt], sl[mt], bsh, bsl);
                }
            }
#pragma unroll
            for (int mt = 0; mt < 2; ++mt)
#pragma unroll
                for (int r = 0; r < 4; ++r) {
                    const float mean = clean_f(fast_tanh(m3[mt][r]));
                    const float ls   = clean_f(s3[mt][r]);
                    const float sd   = fast_softplus(ls);
                    u[mt][r] = fast_tanh(mean + sd * ep[mt][r]);
                }
        }
        {   // B1: h1 = tanh(y @ oW1 + ob1)
            f4v acc[2][4];
#pragma unroll
            for (int mt = 0; mt < 2; ++mt)
#pragma unroll
                for (int nt = 0; nt < 4; ++nt) acc[mt][nt] = splat4(b_o1v[nt]);
#pragma unroll
            for (int kc = 0; kc < 2; ++kc) {
                s8v yh[2], yl[2];
#pragma unroll
                for (int mt = 0; mt < 2; ++mt)
                    ldsPK(&y_pk[(wm * 32 + mt * 16 + lm) * SY + kc * 32 + lg * 8],
                          &yh[mt], &yl[mt]);
#pragma unroll
                for (int nt = 0; nt < 4; ++nt) {
                    const int fb = (((wn * 4 + nt) * 2) + kc) * 64 + l;
                    const s8v bh = o1h[fb], bl = o1l[fb];
#pragma unroll
                    for (int mt = 0; mt < 2; ++mt)
                        MM3(acc[mt][nt], yh[mt], yl[mt], bh, bl);
                }
            }
#pragma unroll
            for (int mt = 0; mt < 2; ++mt)
#pragma unroll
                for (int nt = 0; nt < 4; ++nt)
#pragma unroll
                    for (int r = 0; r < 4; ++r) {
                        const int row = wm * 32 + mt * 16 + lg * 4 + r;
                        const int col = wn * 64 + nt * 16 + lm;
                        h1_pk[row * SH + col] = packsplit(fast_tanh(acc[mt][nt][r]));
                    }
        }
        __syncthreads();

        // ---------- P4: B2 = softplus(h1 @ oW2 + ob2), col-split, o2 in regs ----------
        {
            f4v acc[4][2];
#pragma unroll
            for (int mt = 0; mt < 4; ++mt) {
                acc[mt][0] = splat4(b_o2a);
                acc[mt][1] = splat4(b_o2b);
            }
#pragma unroll
            for (int kc = 0; kc < 8; ++kc) {
                s8v ah[4], al[4];
#pragma unroll
                for (int mt = 0; mt < 4; ++mt)
                    ldsPK(&h1_pk[(mt * 16 + lm) * SH + kc * 32 + lg * 8],
                          &ah[mt], &al[mt]);
#pragma unroll
                for (int mt = 0; mt < 4; ++mt) {
                    MM3(acc[mt][0], ah[mt], al[mt], o2hr[0][kc], o2lr[0][kc]);
                    MM3(acc[mt][1], ah[mt], al[mt], o2hr[1][kc], o2lr[1][kc]);
                }
            }
#pragma unroll
            for (int mt = 0; mt < 4; ++mt)
#pragma unroll
                for (int ntl = 0; ntl < 2; ++ntl)
#pragma unroll
                    for (int r = 0; r < 4; ++r) {
                        const int row = mt * 16 + lg * 4 + r;
                        const int col = (w * 2 + ntl) * 16 + lm;
                        h2_pk[row * SH + col] = packsplit(fast_softplus(acc[mt][ntl][r]));
                    }
        }
        __syncthreads();

        // ---------- P5: B3 = h2 @ oW3 + ob3 ; y += (f - u)*dt ----------
        {
            f4v f3[2] = {splat4(b_o3), splat4(b_o3)};
#pragma unroll
            for (int kc = 0; kc < 8; ++kc) {
                s8v ah[2], al[2];
#pragma unroll
                for (int mt = 0; mt < 2; ++mt)
                    ldsPK(&h2_pk[(wm * 32 + mt * 16 + lm) * SH + kc * 32 + lg * 8],
                          &ah[mt], &al[mt]);
                const int fb = (wn * 8 + kc) * 64 + l;
                const s8v bh = o3h[fb], bl = o3l[fb];
#pragma unroll
                for (int mt = 0; mt < 2; ++mt)
                    MM3(f3[mt], ah[mt], al[mt], bh, bl);
            }
#pragma unroll
            for (int mt = 0; mt < 2; ++mt)
#pragma unroll
                for (int r = 0; r < 4; ++r) {
                    const int row = wm * 32 + mt * 16 + lg * 4 + r;
                    const float yn = ys[mt][r] + (f3[mt][r] - u[mt][r]) * dt;
                    ys[mt][r] = yn;
                    y_pk[row * SY + cN] = packsplit(yn);
                }
        }
        __syncthreads();

        // out[t+1], coalesced from y_pk (hi+lo)
        {
            const int orow = tid >> 3;
            const int oc0 = (tid & 7) * 8;
            const unsigned int* p = &y_pk[orow * SY + oc0];
            float v[8];
#pragma unroll
            for (int j = 0; j < 8; ++j) v[j] = unpacksum(p[j]);
            float4* dst = (float4*)&out[(size_t)(t + 1) * NB * DD +
                                        (size_t)(row0 + orow) * DD + oc0];
            dst[0] = make_float4(v[0], v[1], v[2], v[3]);
            dst[1] = make_float4(v[4], v[5], v[6], v[7]);
        }
    }
}

extern "C" void kernel_launch(void* const* d_in, const int* in_sizes, int n_in,
                              void* d_out, int out_size, void* d_ws, size_t ws_size,
                              hipStream_t stream) {
    const float* y0    = (const float*)d_in[0];
    const float* tarr  = (const float*)d_in[1];
    const float* noise = (const float*)d_in[2];
    const float* oW1 = (const float*)d_in[3];  const float* ob1 = (const float*)d_in[4];
    const float* oW2 = (const float*)d_in[5];  const float* ob2 = (const float*)d_in[6];
    const float* oW3 = (const float*)d_in[7];  const float* ob3 = (const float*)d_in[8];
    const float* amW1 = (const float*)d_in[9];  const float* amb1 = (const float*)d_in[10];
    const float* amW2 = (const float*)d_in[11]; const float* amb2 = (const float*)d_in[12];
    const float* amW3 = (const float*)d_in[13]; const float* amb3 = (const float*)d_in[14];
    const float* asW1 = (const float*)d_in[15]; const float* asb1 = (const float*)d_in[16];
    const float* asW2 = (const float*)d_in[17]; const float* asb2 = (const float*)d_in[18];
    const float* asW3 = (const float*)d_in[19]; const float* asb3 = (const float*)d_in[20];
    float* out = (float*)d_out;
    unsigned short* wsp = (unsigned short*)d_ws;

    // weight swizzle + hi/lo split (step-invariant)
    hipLaunchKernelGGL(prep_kernel, dim3(16 * 2), dim3(64), 0, stream, oW1, 64, 256, wsp + O1H, wsp + O1L);
    hipLaunchKernelGGL(prep_kernel, dim3(16 * 8), dim3(64), 0, stream, oW2, 256, 256, wsp + O2H, wsp + O2L);
    hipLaunchKernelGGL(prep_kernel, dim3(4 * 8),  dim3(64), 0, stream, oW3, 256, 64, wsp + O3H, wsp + O3L);
    hipLaunchKernelGGL(prep_kernel, dim3(4 * 2),  dim3(64), 0, stream, amW1, 64, 64, wsp + AM1H, wsp + AM1L);
    hipLaunchKernelGGL(prep_kernel, dim3(4 * 2),  dim3(64), 0, stream, amW2, 64, 64, wsp + AM2H, wsp + AM2L);
    hipLaunchKernelGGL(prep_kernel, dim3(4 * 2),  dim3(64), 0, stream, amW3, 64, 64, wsp + AM3H, wsp + AM3L);
    hipLaunchKernelGGL(prep_kernel, dim3(4 * 2),  dim3(64), 0, stream, asW1, 64, 64, wsp + AS1H, wsp + AS1L);
    hipLaunchKernelGGL(prep_kernel, dim3(4 * 2),  dim3(64), 0, stream, asW2, 64, 64, wsp + AS2H, wsp + AS2L);
    hipLaunchKernelGGL(prep_kernel, dim3(4 * 2),  dim3(64), 0, stream, asW3, 64, 64, wsp + AS3H, wsp + AS3L);

    hipFuncSetAttribute((const void*)ode_sac_kernel,
                        hipFuncAttributeMaxDynamicSharedMemorySize, LDS_BYTES);

    hipLaunchKernelGGL(ode_sac_kernel, dim3(NB / RB), dim3(NT), LDS_BYTES, stream,
                       y0, tarr, noise,
                       ob1, ob2, ob3, amb1, amb2, amb3, asb1, asb2, asb3,
                       wsp, out);
}

// Round 7
// 2380.794 us; speedup vs baseline: 8.9286x; 1.0222x over previous
//
#include <hip/hip_runtime.h>
#include <hip/hip_bf16.h>
#include <math.h>

#define NB 16384
#define DD 64
#define HH 256
#define NSTEP 63
#define RB 64          // rows per block
#define NT 512         // 8 waves

#define SY 68          // u32 stride, packed y / actor bufs (≡4 mod 32)
#define SH 260         // u32 stride, packed h1/h2 (≡4 mod 32)

// dynamic LDS layout (u32 units)
#define OFF_Y   0
#define OFF_H1  (64 * SY)             // 4352
#define OFF_H2  (OFF_H1 + 64 * SH)    // 20992
#define LDS_U32 (OFF_H2 + 64 * SH)    // 37632
#define LDS_BYTES (LDS_U32 * 4)       // 150528 B -> 1 block/CU (LDS-bound, 2 waves/SIMD)

// d_ws layout (ushort units) — every weight as hi+lo planes in B-frag order
#define O1H 0
#define O1L 16384
#define O2H 32768
#define O2L 98304
#define O3H 163840
#define O3L 180224
#define AM1H 196608
#define AM1L 200704
#define AM2H 204800
#define AM2L 208896
#define AM3H 212992
#define AM3L 217088
#define AS1H 221184
#define AS1L 225280
#define AS2H 229376
#define AS2L 233472
#define AS3H 237568
#define AS3L 241664

typedef __attribute__((ext_vector_type(8))) short s8v;          // 8 bf16
typedef __attribute__((ext_vector_type(4))) float f4v;          // MFMA acc / vec store
typedef __attribute__((ext_vector_type(4))) unsigned int u4v;

#define MFMA(a, b, c) __builtin_amdgcn_mfma_f32_16x16x32_bf16((a), (b), (c), 0, 0, 0)
// 3-term split product: A*B ≈ Ah*Bh + Ah*Bl + Al*Bh   (residual ~2^-18)
#define MM3(acc, ah, al, bh, bl)                                 \
    do {                                                         \
        acc = MFMA(ah, bh, acc);                                 \
        acc = MFMA(ah, bl, acc);                                 \
        acc = MFMA(al, bh, acc);                                 \
    } while (0)

// opaque def: compiler cannot rematerialize/reload this value inside the t-loop.
// VGPR is cheap here (LDS-bound occupancy: 2 waves/SIMD regardless, up to 512 VGPR).
__device__ __forceinline__ void pin(s8v& x) { asm volatile("" : "+v"(x)); }

__device__ __forceinline__ unsigned short f2b(float x) {
    return __builtin_bit_cast(unsigned short, (__bf16)x);
}
__device__ __forceinline__ float b2f(unsigned short u) {
    return __builtin_bit_cast(float, (unsigned int)u << 16);
}
__device__ __forceinline__ unsigned int packsplit(float x) {
    const unsigned short hi = f2b(x);
    const unsigned short lo = f2b(x - b2f(hi));
    return (unsigned int)hi | ((unsigned int)lo << 16);
}
__device__ __forceinline__ float unpacksum(unsigned int pk) {
    return b2f((unsigned short)(pk & 0xFFFFu)) + b2f((unsigned short)(pk >> 16));
}
__device__ __forceinline__ float fast_tanh(float x) {
    float e = __expf(-2.0f * fabsf(x));
    float r = __fdividef(1.0f - e, 1.0f + e);
    return copysignf(r, x);
}
__device__ __forceinline__ float fast_softplus(float x) {
    return fmaxf(x, 0.0f) + __logf(1.0f + __expf(-fabsf(x)));
}
__device__ __forceinline__ float clean_f(float x) { return isfinite(x) ? x : 0.0f; }
__device__ __forceinline__ f4v splat4(float b) { f4v v = {b, b, b, b}; return v; }

// read 8 packed u32 (hi|lo), unpack to hi/lo bf16 A-fragments
__device__ __forceinline__ void ldsPK(const unsigned int* p, s8v* hi, s8v* lo) {
    const u4v q0 = *(const u4v*)p;
    const u4v q1 = *(const u4v*)(p + 4);
    union { unsigned int u[4]; s8v v; } H, L;
    H.u[0] = __builtin_amdgcn_perm(q0[1], q0[0], 0x05040100);
    L.u[0] = __builtin_amdgcn_perm(q0[1], q0[0], 0x07060302);
    H.u[1] = __builtin_amdgcn_perm(q0[3], q0[2], 0x05040100);
    L.u[1] = __builtin_amdgcn_perm(q0[3], q0[2], 0x07060302);
    H.u[2] = __builtin_amdgcn_perm(q1[1], q1[0], 0x05040100);
    L.u[2] = __builtin_amdgcn_perm(q1[1], q1[0], 0x07060302);
    H.u[3] = __builtin_amdgcn_perm(q1[3], q1[2], 0x05040100);
    L.u[3] = __builtin_amdgcn_perm(q1[3], q1[2], 0x07060302);
    *hi = H.v; *lo = L.v;
}

// swizzle W[K x N] f32 into B-fragment order, split bf16 hi+lo
__global__ void prep_kernel(const float* __restrict__ W, int K, int N,
                            unsigned short* __restrict__ hi,
                            unsigned short* __restrict__ lo) {
    const int l = threadIdx.x;            // 64
    const int kcN = K >> 5;
    const int nt = blockIdx.x / kcN;
    const int kc = blockIdx.x % kcN;
    const int col = nt * 16 + (l & 15);
    const int k0 = kc * 32 + ((l >> 4) << 3);
    const size_t base = ((size_t)(nt * kcN + kc) * 64 + l) * 8;
#pragma unroll
    for (int b = 0; b < 8; ++b) {
        float wv = W[(size_t)(k0 + b) * N + col];
        unsigned short h = f2b(wv);
        hi[base + b] = h;
        lo[base + b] = f2b(wv - b2f(h));
    }
}

extern "C" __global__ void __launch_bounds__(NT, 2)
ode_sac_kernel(const float* __restrict__ y0,
               const float* __restrict__ tarr,
               const float* __restrict__ noise,
               const float* __restrict__ ob1, const float* __restrict__ ob2,
               const float* __restrict__ ob3,
               const float* __restrict__ amb1, const float* __restrict__ amb2,
               const float* __restrict__ amb3,
               const float* __restrict__ asb1, const float* __restrict__ asb2,
               const float* __restrict__ asb3,
               const unsigned short* __restrict__ ws,
               float* __restrict__ out) {
    extern __shared__ unsigned int smem[];
    unsigned int* y_pk  = smem + OFF_Y;    // [64 rows][stride SY]
    unsigned int* h1_pk = smem + OFF_H1;   // [64][SH]
    unsigned int* h2_pk = smem + OFF_H2;   // [64][SH]
    unsigned int* a1m = h1_pk;             // [64][SY] carved from h1
    unsigned int* a1s = h1_pk + 64 * SY;
    unsigned int* a2m = h2_pk;             // carved from h2
    unsigned int* a2s = h2_pk + 64 * SY;

    const int tid = threadIdx.x;
    const int w  = tid >> 6;       // wave 0..7
    const int l  = tid & 63;
    const int lm = l & 15;
    const int lg = l >> 4;
    const int wm = w >> 2;         // M-half (narrow layers): rows wm*32..+31
    const int wn = w & 3;          // n-tile (narrow layers)
    const int row0 = blockIdx.x * RB;
    const int cN = wn * 16 + lm;   // narrow-layer / B3 ownership column

    const float dt = tarr[1] - tarr[0];

    // fragment plane base pointers (global)
    const s8v* o1h = (const s8v*)(ws + O1H); const s8v* o1l = (const s8v*)(ws + O1L);
    const s8v* o2h = (const s8v*)(ws + O2H); const s8v* o2l = (const s8v*)(ws + O2L);
    const s8v* o3h = (const s8v*)(ws + O3H); const s8v* o3l = (const s8v*)(ws + O3L);
    const s8v* am1h = (const s8v*)(ws + AM1H); const s8v* am1l = (const s8v*)(ws + AM1L);
    const s8v* am2h = (const s8v*)(ws + AM2H); const s8v* am2l = (const s8v*)(ws + AM2L);
    const s8v* am3h = (const s8v*)(ws + AM3H); const s8v* am3l = (const s8v*)(ws + AM3L);
    const s8v* as1h = (const s8v*)(ws + AS1H); const s8v* as1l = (const s8v*)(ws + AS1L);
    const s8v* as2h = (const s8v*)(ws + AS2H); const s8v* as2l = (const s8v*)(ws + AS2L);
    const s8v* as3h = (const s8v*)(ws + AS3H); const s8v* as3l = (const s8v*)(ws + AS3L);

    // ================= persist ALL weight fragments in registers =================
    // 88 s8v = 352 VGPR, pinned with opaque defs so they survive the t-loop.
    s8v am1h_r[2], am1l_r[2], am2h_r[2], am2l_r[2], am3h_r[2], am3l_r[2];
    s8v as1h_r[2], as1l_r[2], as2h_r[2], as2l_r[2], as3h_r[2], as3l_r[2];
#pragma unroll
    for (int kc = 0; kc < 2; ++kc) {
        const int fb = (wn * 2 + kc) * 64 + l;
        am1h_r[kc] = am1h[fb]; am1l_r[kc] = am1l[fb];
        am2h_r[kc] = am2h[fb]; am2l_r[kc] = am2l[fb];
        am3h_r[kc] = am3h[fb]; am3l_r[kc] = am3l[fb];
        as1h_r[kc] = as1h[fb]; as1l_r[kc] = as1l[fb];
        as2h_r[kc] = as2h[fb]; as2l_r[kc] = as2l[fb];
        as3h_r[kc] = as3h[fb]; as3l_r[kc] = as3l[fb];
        pin(am1h_r[kc]); pin(am1l_r[kc]); pin(am2h_r[kc]); pin(am2l_r[kc]);
        pin(am3h_r[kc]); pin(am3l_r[kc]); pin(as1h_r[kc]); pin(as1l_r[kc]);
        pin(as2h_r[kc]); pin(as2l_r[kc]); pin(as3h_r[kc]); pin(as3l_r[kc]);
    }
    s8v o1h_r[4][2], o1l_r[4][2];
#pragma unroll
    for (int nt = 0; nt < 4; ++nt)
#pragma unroll
        for (int kc = 0; kc < 2; ++kc) {
            const int fb = (((wn * 4 + nt) * 2) + kc) * 64 + l;
            o1h_r[nt][kc] = o1h[fb]; o1l_r[nt][kc] = o1l[fb];
            pin(o1h_r[nt][kc]); pin(o1l_r[nt][kc]);
        }
    s8v o2h_r[2][8], o2l_r[2][8];
#pragma unroll
    for (int ntl = 0; ntl < 2; ++ntl)
#pragma unroll
        for (int kc = 0; kc < 8; ++kc) {
            const int fb = ((w * 2 + ntl) * 8 + kc) * 64 + l;
            o2h_r[ntl][kc] = o2h[fb]; o2l_r[ntl][kc] = o2l[fb];
            pin(o2h_r[ntl][kc]); pin(o2l_r[ntl][kc]);
        }
    s8v o3h_r[8], o3l_r[8];
#pragma unroll
    for (int kc = 0; kc < 8; ++kc) {
        const int fb = (wn * 8 + kc) * 64 + l;
        o3h_r[kc] = o3h[fb]; o3l_r[kc] = o3l[fb];
        pin(o3h_r[kc]); pin(o3l_r[kc]);
    }

    // biases
    const float b_am1 = amb1[cN], b_am2 = amb2[cN], b_am3 = amb3[cN];
    const float b_as1 = asb1[cN], b_as2 = asb2[cN], b_as3 = asb3[cN];
    const float b_o3  = ob3[cN];
    const float b_o2a = ob2[(w * 2) * 16 + lm];
    const float b_o2b = ob2[(w * 2 + 1) * 16 + lm];
    float b_o1v[4];
#pragma unroll
    for (int nt = 0; nt < 4; ++nt) b_o1v[nt] = ob1[wn * 64 + nt * 16 + lm];

    // y state in registers (exact f32): element (mt,r) at row wm*32+mt*16+lg*4+r, col cN
    float ys[2][4];
#pragma unroll
    for (int mt = 0; mt < 2; ++mt)
#pragma unroll
        for (int r = 0; r < 4; ++r) {
            const int row = wm * 32 + mt * 16 + lg * 4 + r;
            const float v = y0[(size_t)(row0 + row) * DD + cN];
            ys[mt][r] = v;
            y_pk[row * SY + cN] = packsplit(v);
        }
    __syncthreads();

    // out[0] = y0, coalesced via y_pk (hi+lo, err ~2e-3); nontemporal (keep L2 clean)
    {
        const int orow = tid >> 3;
        const int oc0 = (tid & 7) * 8;
        const unsigned int* p = &y_pk[orow * SY + oc0];
        float v[8];
#pragma unroll
        for (int j = 0; j < 8; ++j) v[j] = unpacksum(p[j]);
        f4v* dst = (f4v*)&out[(size_t)(row0 + orow) * DD + oc0];
        f4v v0 = {v[0], v[1], v[2], v[3]};
        f4v v1 = {v[4], v[5], v[6], v[7]};
        __builtin_nontemporal_store(v0, dst);
        __builtin_nontemporal_store(v1, dst + 1);
    }

    for (int t = 0; t < NSTEP; ++t) {
        // noise prefetch (used in P3); nontemporal — pure stream, don't thrash L2
        float ep[2][4];
#pragma unroll
        for (int mt = 0; mt < 2; ++mt)
#pragma unroll
            for (int r = 0; r < 4; ++r) {
                const int row = wm * 32 + mt * 16 + lg * 4 + r;
                ep[mt][r] = __builtin_nontemporal_load(
                    &noise[(size_t)t * NB * DD + (size_t)(row0 + row) * DD + cN]);
            }

        // ---------- P1: A1 & S1 = relu(y @ W1 + b), 3-term ----------
        {
            f4v am[2] = {splat4(b_am1), splat4(b_am1)};
            f4v as[2] = {splat4(b_as1), splat4(b_as1)};
#pragma unroll
            for (int kc = 0; kc < 2; ++kc) {
                s8v yh[2], yl[2];
#pragma unroll
                for (int mt = 0; mt < 2; ++mt)
                    ldsPK(&y_pk[(wm * 32 + mt * 16 + lm) * SY + kc * 32 + lg * 8],
                          &yh[mt], &yl[mt]);
#pragma unroll
                for (int mt = 0; mt < 2; ++mt) {
                    MM3(am[mt], yh[mt], yl[mt], am1h_r[kc], am1l_r[kc]);
                    MM3(as[mt], yh[mt], yl[mt], as1h_r[kc], as1l_r[kc]);
                }
            }
#pragma unroll
            for (int mt = 0; mt < 2; ++mt)
#pragma unroll
                for (int r = 0; r < 4; ++r) {
                    const int row = wm * 32 + mt * 16 + lg * 4 + r;
                    a1m[row * SY + cN] = packsplit(fmaxf(am[mt][r], 0.0f));
                    a1s[row * SY + cN] = packsplit(fmaxf(as[mt][r], 0.0f));
                }
        }
        __syncthreads();

        // ---------- P2: A2 & S2 ----------
        {
            f4v am[2] = {splat4(b_am2), splat4(b_am2)};
            f4v as[2] = {splat4(b_as2), splat4(b_as2)};
#pragma unroll
            for (int kc = 0; kc < 2; ++kc) {
                const int k0 = kc * 32 + lg * 8;
                s8v mh[2], ml[2], sh[2], sl[2];
#pragma unroll
                for (int mt = 0; mt < 2; ++mt) {
                    const int rr = (wm * 32 + mt * 16 + lm) * SY + k0;
                    ldsPK(&a1m[rr], &mh[mt], &ml[mt]);
                    ldsPK(&a1s[rr], &sh[mt], &sl[mt]);
                }
#pragma unroll
                for (int mt = 0; mt < 2; ++mt) {
                    MM3(am[mt], mh[mt], ml[mt], am2h_r[kc], am2l_r[kc]);
                    MM3(as[mt], sh[mt], sl[mt], as2h_r[kc], as2l_r[kc]);
                }
            }
#pragma unroll
            for (int mt = 0; mt < 2; ++mt)
#pragma unroll
                for (int r = 0; r < 4; ++r) {
                    const int row = wm * 32 + mt * 16 + lg * 4 + r;
                    a2m[row * SY + cN] = packsplit(fmaxf(am[mt][r], 0.0f));
                    a2s[row * SY + cN] = packsplit(fmaxf(as[mt][r], 0.0f));
                }
        }
        __syncthreads();

        // ---------- P3: A3 & S3 -> u (regs);  B1 -> h1 ----------
        float u[2][4];
        {
            f4v m3[2] = {splat4(b_am3), splat4(b_am3)};
            f4v s3[2] = {splat4(b_as3), splat4(b_as3)};
#pragma unroll
            for (int kc = 0; kc < 2; ++kc) {
                const int k0 = kc * 32 + lg * 8;
                s8v mh[2], ml[2], sh[2], sl[2];
#pragma unroll
                for (int mt = 0; mt < 2; ++mt) {
                    const int rr = (wm * 32 + mt * 16 + lm) * SY + k0;
                    ldsPK(&a2m[rr], &mh[mt], &ml[mt]);
                    ldsPK(&a2s[rr], &sh[mt], &sl[mt]);
                }
#pragma unroll
                for (int mt = 0; mt < 2; ++mt) {
                    MM3(m3[mt], mh[mt], ml[mt], am3h_r[kc], am3l_r[kc]);
                    MM3(s3[mt], sh[mt], sl[mt], as3h_r[kc], as3l_r[kc]);
                }
            }
#pragma unroll
            for (int mt = 0; mt < 2; ++mt)
#pragma unroll
                for (int r = 0; r < 4; ++r) {
                    const float mean = clean_f(fast_tanh(m3[mt][r]));
                    const float ls   = clean_f(s3[mt][r]);
                    const float sd   = fast_softplus(ls);
                    u[mt][r] = fast_tanh(mean + sd * ep[mt][r]);
                }
        }
        {   // B1: h1 = tanh(y @ oW1 + ob1)
            f4v acc[2][4];
#pragma unroll
            for (int mt = 0; mt < 2; ++mt)
#pragma unroll
                for (int nt = 0; nt < 4; ++nt) acc[mt][nt] = splat4(b_o1v[nt]);
#pragma unroll
            for (int kc = 0; kc < 2; ++kc) {
                s8v yh[2], yl[2];
#pragma unroll
                for (int mt = 0; mt < 2; ++mt)
                    ldsPK(&y_pk[(wm * 32 + mt * 16 + lm) * SY + kc * 32 + lg * 8],
                          &yh[mt], &yl[mt]);
#pragma unroll
                for (int nt = 0; nt < 4; ++nt) {
#pragma unroll
                    for (int mt = 0; mt < 2; ++mt)
                        MM3(acc[mt][nt], yh[mt], yl[mt], o1h_r[nt][kc], o1l_r[nt][kc]);
                }
            }
#pragma unroll
            for (int mt = 0; mt < 2; ++mt)
#pragma unroll
                for (int nt = 0; nt < 4; ++nt)
#pragma unroll
                    for (int r = 0; r < 4; ++r) {
                        const int row = wm * 32 + mt * 16 + lg * 4 + r;
                        const int col = wn * 64 + nt * 16 + lm;
                        h1_pk[row * SH + col] = packsplit(fast_tanh(acc[mt][nt][r]));
                    }
        }
        __syncthreads();

        // ---------- P4: B2 = softplus(h1 @ oW2 + ob2), col-split, o2 in regs ----------
        {
            f4v acc[4][2];
#pragma unroll
            for (int mt = 0; mt < 4; ++mt) {
                acc[mt][0] = splat4(b_o2a);
                acc[mt][1] = splat4(b_o2b);
            }
#pragma unroll
            for (int kc = 0; kc < 8; ++kc) {
                s8v ah[4], al[4];
#pragma unroll
                for (int mt = 0; mt < 4; ++mt)
                    ldsPK(&h1_pk[(mt * 16 + lm) * SH + kc * 32 + lg * 8],
                          &ah[mt], &al[mt]);
#pragma unroll
                for (int mt = 0; mt < 4; ++mt) {
                    MM3(acc[mt][0], ah[mt], al[mt], o2h_r[0][kc], o2l_r[0][kc]);
                    MM3(acc[mt][1], ah[mt], al[mt], o2h_r[1][kc], o2l_r[1][kc]);
                }
            }
#pragma unroll
            for (int mt = 0; mt < 4; ++mt)
#pragma unroll
                for (int ntl = 0; ntl < 2; ++ntl)
#pragma unroll
                    for (int r = 0; r < 4; ++r) {
                        const int row = mt * 16 + lg * 4 + r;
                        const int col = (w * 2 + ntl) * 16 + lm;
                        h2_pk[row * SH + col] = packsplit(fast_softplus(acc[mt][ntl][r]));
                    }
        }
        __syncthreads();

        // ---------- P5: B3 = h2 @ oW3 + ob3 ; y += (f - u)*dt ----------
        {
            f4v f3[2] = {splat4(b_o3), splat4(b_o3)};
#pragma unroll
            for (int kc = 0; kc < 8; ++kc) {
                s8v ah[2], al[2];
#pragma unroll
                for (int mt = 0; mt < 2; ++mt)
                    ldsPK(&h2_pk[(wm * 32 + mt * 16 + lm) * SH + kc * 32 + lg * 8],
                          &ah[mt], &al[mt]);
#pragma unroll
                for (int mt = 0; mt < 2; ++mt)
                    MM3(f3[mt], ah[mt], al[mt], o3h_r[kc], o3l_r[kc]);
            }
#pragma unroll
            for (int mt = 0; mt < 2; ++mt)
#pragma unroll
                for (int r = 0; r < 4; ++r) {
                    const int row = wm * 32 + mt * 16 + lg * 4 + r;
                    const float yn = ys[mt][r] + (f3[mt][r] - u[mt][r]) * dt;
                    ys[mt][r] = yn;
                    y_pk[row * SY + cN] = packsplit(yn);
                }
        }
        __syncthreads();

        // out[t+1], coalesced from y_pk (hi+lo), nontemporal
        {
            const int orow = tid >> 3;
            const int oc0 = (tid & 7) * 8;
            const unsigned int* p = &y_pk[orow * SY + oc0];
            float v[8];
#pragma unroll
            for (int j = 0; j < 8; ++j) v[j] = unpacksum(p[j]);
            f4v* dst = (f4v*)&out[(size_t)(t + 1) * NB * DD +
                                  (size_t)(row0 + orow) * DD + oc0];
            f4v v0 = {v[0], v[1], v[2], v[3]};
            f4v v1 = {v[4], v[5], v[6], v[7]};
            __builtin_nontemporal_store(v0, dst);
            __builtin_nontemporal_store(v1, dst + 1);
        }
    }
}

extern "C" void kernel_launch(void* const* d_in, const int* in_sizes, int n_in,
                              void* d_out, int out_size, void* d_ws, size_t ws_size,
                              hipStream_t stream) {
    const float* y0    = (const float*)d_in[0];
    const float* tarr  = (const float*)d_in[1];
    const float* noise = (const float*)d_in[2];
    const float* oW1 = (const float*)d_in[3];  const float* ob1 = (const float*)d_in[4];
    const float* oW2 = (const float*)d_in[5];  const float* ob2 = (const float*)d_in[6];
    const float* oW3 = (const float*)d_in[7];  const float* ob3 = (const float*)d_in[8];
    const float* amW1 = (const float*)d_in[9];  const float* amb1 = (const float*)d_in[10];
    const float* amW2 = (const float*)d_in[11]; const float* amb2 = (const float*)d_in[12];
    const float* amW3 = (const float*)d_in[13]; const float* amb3 = (const float*)d_in[14];
    const float* asW1 = (const float*)d_in[15]; const float* asb1 = (const float*)d_in[16];
    const float* asW2 = (const float*)d_in[17]; const float* asb2 = (const float*)d_in[18];
    const float* asW3 = (const float*)d_in[19]; const float* asb3 = (const float*)d_in[20];
    float* out = (float*)d_out;
    unsigned short* wsp = (unsigned short*)d_ws;

    // weight swizzle + hi/lo split (step-invariant)
    hipLaunchKernelGGL(prep_kernel, dim3(16 * 2), dim3(64), 0, stream, oW1, 64, 256, wsp + O1H, wsp + O1L);
    hipLaunchKernelGGL(prep_kernel, dim3(16 * 8), dim3(64), 0, stream, oW2, 256, 256, wsp + O2H, wsp + O2L);
    hipLaunchKernelGGL(prep_kernel, dim3(4 * 8),  dim3(64), 0, stream, oW3, 256, 64, wsp + O3H, wsp + O3L);
    hipLaunchKernelGGL(prep_kernel, dim3(4 * 2),  dim3(64), 0, stream, amW1, 64, 64, wsp + AM1H, wsp + AM1L);
    hipLaunchKernelGGL(prep_kernel, dim3(4 * 2),  dim3(64), 0, stream, amW2, 64, 64, wsp + AM2H, wsp + AM2L);
    hipLaunchKernelGGL(prep_kernel, dim3(4 * 2),  dim3(64), 0, stream, amW3, 64, 64, wsp + AM3H, wsp + AM3L);
    hipLaunchKernelGGL(prep_kernel, dim3(4 * 2),  dim3(64), 0, stream, asW1, 64, 64, wsp + AS1H, wsp + AS1L);
    hipLaunchKernelGGL(prep_kernel, dim3(4 * 2),  dim3(64), 0, stream, asW2, 64, 64, wsp + AS2H, wsp + AS2L);
    hipLaunchKernelGGL(prep_kernel, dim3(4 * 2),  dim3(64), 0, stream, asW3, 64, 64, wsp + AS3H, wsp + AS3L);

    (void)hipFuncSetAttribute((const void*)ode_sac_kernel,
                              hipFuncAttributeMaxDynamicSharedMemorySize, LDS_BYTES);

    hipLaunchKernelGGL(ode_sac_kernel, dim3(NB / RB), dim3(NT), LDS_BYTES, stream,
                       y0, tarr, noise,
                       ob1, ob2, ob3, amb1, amb2, amb3, asb1, asb2, asb3,
                       wsp, out);
}